// Round 7
// baseline (330.266 us; speedup 1.0000x reference)
//
#include <hip/hip_runtime.h>

#define DIM 128      // feature dim, fixed per reference
#define GTM 32       // gemm tile rows
#define GTN 128      // gemm tile cols (= DIM, A read once)
#define HB  248      // histogram copies ~= CU count (1 block/CU due to 100KB LDS)
#define HWORDS 25088 // max (N+1)/2 supported by LDS histogram (100,352 B)

// ---------------- LDS-privatized dual histogram + rank capture ----------------
// Each block: slice of edges -> LDS histogram (2x16-bit counters/word).
// dst phase captures per-slice rank; src phase counts only.
// Private copies streamed to global with plain stores -> zero global atomics.
__global__ __launch_bounds__(256) void k_hist(const int* __restrict__ src,
                                              const int* __restrict__ dst,
                                              unsigned short* __restrict__ local,
                                              unsigned* __restrict__ hist_in,
                                              unsigned* __restrict__ hist_out,
                                              int E, int W2, int slice) {
    __shared__ unsigned h[HWORDS];
    const int t = threadIdx.x;
    const int b = blockIdx.x;
    const int e0 = b * slice;
    const int e1 = min(e0 + slice, E);

    for (int w = t; w < W2; w += 256) h[w] = 0u;
    __syncthreads();
    // dst histogram with rank capture
    for (int e = e0 + t; e < e1; e += 256) {
        int d = dst[e];
        unsigned sh = (unsigned)(d & 1) * 16u;
        unsigned old = atomicAdd(&h[d >> 1], 1u << sh);
        local[e] = (unsigned short)((old >> sh) & 0xffffu);
    }
    __syncthreads();
    unsigned* oin = hist_in + (size_t)b * W2;
    for (int w = t; w < W2; w += 256) { oin[w] = h[w]; h[w] = 0u; }
    __syncthreads();
    // src histogram (no rank)
    for (int e = e0 + t; e < e1; e += 256) {
        int s = src[e];
        atomicAdd(&h[s >> 1], 1u << ((unsigned)(s & 1) * 16u));
    }
    __syncthreads();
    unsigned* oout = hist_out + (size_t)b * W2;
    for (int w = t; w < W2; w += 256) oout[w] = h[w];
}

// ---------------- column scan: per-node exclusive prefix across HB copies ----------------
__global__ __launch_bounds__(256) void k_colscan(unsigned* __restrict__ hist_in,
                                                 const unsigned* __restrict__ hist_out,
                                                 int* __restrict__ cnt,
                                                 int* __restrict__ deg_out,
                                                 int W2, int N, int nb) {
    int w = blockIdx.x * 256 + threadIdx.x;
    if (w >= W2) return;
    unsigned run = 0;
    #pragma unroll 4
    for (int b = 0; b < nb; ++b) {
        unsigned* p = hist_in + (size_t)b * W2 + w;
        unsigned x = *p;
        *p = run;          // exclusive packed prefix
        run += x;          // halves independent (each < 65536)
    }
    unsigned run2 = 0;
    #pragma unroll 4
    for (int b = 0; b < nb; ++b) run2 += hist_out[(size_t)b * W2 + w];
    int n0 = w * 2, n1 = n0 + 1;
    cnt[n0] = (int)(run & 0xffffu);
    deg_out[n0] = (int)(run2 & 0xffffu);
    if (n1 < N) {
        cnt[n1] = (int)(run >> 16);
        deg_out[n1] = (int)(run2 >> 16);
    }
}

// ---------------- fallback edge pass (global atomics) for oversized N ----------------
__global__ __launch_bounds__(256) void k_edge_pass_fb(const int* __restrict__ src,
                                                      const int* __restrict__ dst,
                                                      int* __restrict__ deg_out,
                                                      int* __restrict__ cnt,
                                                      int* __restrict__ local_fb, int E) {
    int e = blockIdx.x * 256 + threadIdx.x;
    if (e < E) {
        atomicAdd(&deg_out[src[e]], 1);
        local_fb[e] = atomicAdd(&cnt[dst[e]], 1);
    }
}

// ---------------- scan step 1: per-block sums of cnt ----------------
__global__ __launch_bounds__(256) void k_block_reduce(const int* __restrict__ deg,
                                                      int* __restrict__ bsum, int N) {
    __shared__ int wsum[4];
    int i = blockIdx.x * 256 + threadIdx.x;
    int x = (i < N) ? deg[i] : 0;
    #pragma unroll
    for (int off = 32; off > 0; off >>= 1) x += __shfl_down(x, off, 64);
    int lane = threadIdx.x & 63, wave = threadIdx.x >> 6;
    if (lane == 0) wsum[wave] = x;
    __syncthreads();
    if (threadIdx.x == 0) bsum[blockIdx.x] = wsum[0] + wsum[1] + wsum[2] + wsum[3];
}

// ---------------- scan step 2: exclusive scan of block sums (1 block) ----------------
__global__ __launch_bounds__(256) void k_scan_small(const int* __restrict__ bsum,
                                                    int* __restrict__ bpre, int B) {
    __shared__ int wsum[4];
    __shared__ int carry_s;
    if (threadIdx.x == 0) carry_s = 0;
    __syncthreads();
    int lane = threadIdx.x & 63, wave = threadIdx.x >> 6;
    for (int base = 0; base < B; base += 256) {
        int i = base + threadIdx.x;
        int x = (i < B) ? bsum[i] : 0;
        int orig = x;
        #pragma unroll
        for (int off = 1; off < 64; off <<= 1) {
            int y = __shfl_up(x, off, 64);
            if (lane >= off) x += y;
        }
        if (lane == 63) wsum[wave] = x;
        __syncthreads();
        if (threadIdx.x == 0) {
            int s = 0;
            for (int w = 0; w < 4; ++w) { int t = wsum[w]; wsum[w] = s; s += t; }
        }
        __syncthreads();
        x += wsum[wave] + carry_s;
        if (i < B) bpre[i] = x - orig;
        __syncthreads();
        if (threadIdx.x == 255) carry_s = x;
        __syncthreads();
    }
}

// ---------------- scan step 3: row_off + both norms (fused) ----------------
__global__ __launch_bounds__(256) void k_scan_final(const int* __restrict__ cnt,
                                                    const int* __restrict__ deg_out,
                                                    const int* __restrict__ bpre,
                                                    int* __restrict__ row_off,
                                                    float* __restrict__ norm_src,
                                                    float* __restrict__ norm_dst, int N) {
    __shared__ int wsum[4];
    int i = blockIdx.x * 256 + threadIdx.x;
    int x = (i < N) ? cnt[i] : 0;
    int orig = x;
    int lane = threadIdx.x & 63, wave = threadIdx.x >> 6;
    #pragma unroll
    for (int off = 1; off < 64; off <<= 1) {
        int y = __shfl_up(x, off, 64);
        if (lane >= off) x += y;
    }
    if (lane == 63) wsum[wave] = x;
    __syncthreads();
    if (threadIdx.x == 0) {
        int s = 0;
        for (int w = 0; w < 4; ++w) { int t = wsum[w]; wsum[w] = s; s += t; }
    }
    __syncthreads();
    x += wsum[wave] + bpre[blockIdx.x];
    if (i < N) {
        row_off[i] = x - orig;                    // exclusive prefix
        int di = orig < 1 ? 1 : orig;             // deg_in clamp
        norm_dst[i] = rsqrtf((float)di);
        int dov = deg_out[i]; if (dov < 1) dov = 1;
        norm_src[i] = rsqrtf((float)dov);
    }
    if (i == N - 1) row_off[N] = x;               // total
}

// ---------------- CSR fill: pure scatter, no atomics ----------------
__global__ __launch_bounds__(256) void k_fill(const int* __restrict__ src,
                                              const int* __restrict__ dst,
                                              const int* __restrict__ row_off,
                                              const unsigned short* __restrict__ local,
                                              const int* __restrict__ local_fb,
                                              const unsigned* __restrict__ hist_in,
                                              int* __restrict__ csr_src,
                                              int E, int W2, int slice) {
    int e = blockIdx.x * 256 + threadIdx.x;
    if (e < E) {
        int d = dst[e];
        int pos = row_off[d];
        if (hist_in) {
            int b = e / slice;
            unsigned bo = (hist_in[(size_t)b * W2 + (d >> 1)] >> ((unsigned)(d & 1) * 16u)) & 0xffffu;
            pos += (int)bo + (int)local[e];
        } else {
            pos += local_fb[e];
        }
        csr_src[pos] = src[e];
    }
}

// ---------------- CSR SpMM: agg[d] = nd[d] * sum_s w(s)*h[s] ----------------
// 32 lanes per node, float4 per lane; 4-deep unroll, dual acc chains.
// norm_src == nullptr => gather source is pre-scaled (layer 2), skip the loads.
__global__ __launch_bounds__(256) void k_spmm(const float* __restrict__ h,
                                              const int* __restrict__ csr_src,
                                              const int* __restrict__ row_off,
                                              const float* __restrict__ norm_src,
                                              const float* __restrict__ norm_dst,
                                              float* __restrict__ agg, int N) {
    int t = blockIdx.x * 256 + threadIdx.x;
    int node = t >> 5;
    int lane = t & 31;
    if (node >= N) return;
    int beg = row_off[node], end = row_off[node + 1];
    float4 acc0 = make_float4(0.f, 0.f, 0.f, 0.f);
    float4 acc1 = make_float4(0.f, 0.f, 0.f, 0.f);
    int i = beg;
    if (norm_src) {
        for (; i + 4 <= end; i += 4) {
            int s0 = csr_src[i], s1 = csr_src[i + 1], s2 = csr_src[i + 2], s3 = csr_src[i + 3];
            float n0 = norm_src[s0], n1 = norm_src[s1], n2 = norm_src[s2], n3 = norm_src[s3];
            float4 v0 = *((const float4*)(h + (size_t)s0 * DIM) + lane);
            float4 v1 = *((const float4*)(h + (size_t)s1 * DIM) + lane);
            float4 v2 = *((const float4*)(h + (size_t)s2 * DIM) + lane);
            float4 v3 = *((const float4*)(h + (size_t)s3 * DIM) + lane);
            acc0.x += v0.x * n0; acc0.y += v0.y * n0; acc0.z += v0.z * n0; acc0.w += v0.w * n0;
            acc1.x += v1.x * n1; acc1.y += v1.y * n1; acc1.z += v1.z * n1; acc1.w += v1.w * n1;
            acc0.x += v2.x * n2; acc0.y += v2.y * n2; acc0.z += v2.z * n2; acc0.w += v2.w * n2;
            acc1.x += v3.x * n3; acc1.y += v3.y * n3; acc1.z += v3.z * n3; acc1.w += v3.w * n3;
        }
        for (; i < end; ++i) {
            int s0 = csr_src[i];
            float n0 = norm_src[s0];
            float4 v0 = *((const float4*)(h + (size_t)s0 * DIM) + lane);
            acc0.x += v0.x * n0; acc0.y += v0.y * n0; acc0.z += v0.z * n0; acc0.w += v0.w * n0;
        }
    } else {
        for (; i + 4 <= end; i += 4) {
            int s0 = csr_src[i], s1 = csr_src[i + 1], s2 = csr_src[i + 2], s3 = csr_src[i + 3];
            float4 v0 = *((const float4*)(h + (size_t)s0 * DIM) + lane);
            float4 v1 = *((const float4*)(h + (size_t)s1 * DIM) + lane);
            float4 v2 = *((const float4*)(h + (size_t)s2 * DIM) + lane);
            float4 v3 = *((const float4*)(h + (size_t)s3 * DIM) + lane);
            acc0.x += v0.x; acc0.y += v0.y; acc0.z += v0.z; acc0.w += v0.w;
            acc1.x += v1.x; acc1.y += v1.y; acc1.z += v1.z; acc1.w += v1.w;
            acc0.x += v2.x; acc0.y += v2.y; acc0.z += v2.z; acc0.w += v2.w;
            acc1.x += v3.x; acc1.y += v3.y; acc1.z += v3.z; acc1.w += v3.w;
        }
        for (; i < end; ++i) {
            int s0 = csr_src[i];
            float4 v0 = *((const float4*)(h + (size_t)s0 * DIM) + lane);
            acc0.x += v0.x; acc0.y += v0.y; acc0.z += v0.z; acc0.w += v0.w;
        }
    }
    float nd = norm_dst[node];
    float4 o;
    o.x = (acc0.x + acc1.x) * nd;
    o.y = (acc0.y + acc1.y) * nd;
    o.z = (acc0.z + acc1.z) * nd;
    o.w = (acc0.w + acc1.w) * nd;
    *((float4*)(agg + (size_t)node * DIM) + lane) = o;
}

// ---------------- fused: out = [postscale ⊙] relu(agg @ W + b) ----------------
// 32x128 tile, 256 threads, 4x4 acc/thread; full W in LDS; 2 blocks/CU.
// postscale (norm_src) folds next layer's source scaling into the epilogue.
__global__ __launch_bounds__(256, 2) void k_gemm_bias_relu(
        const float* __restrict__ A, const float* __restrict__ W,
        const float* __restrict__ bias, const float* __restrict__ postscale,
        float* __restrict__ out, int N) {
    __shared__ float Ws[DIM * GTN];   // [k][c] 64 KB
    __shared__ float As[GTM * 68];    // [r][64-k chunk], stride 68

    const int t = threadIdx.x;
    const int row0 = blockIdx.x * GTM;

    #pragma unroll
    for (int i = 0; i < 16; ++i) {
        int idx = (t + i * 256) * 4;
        *(float4*)(Ws + idx) = *(const float4*)(W + idx);
    }

    const int tx = t & 31;    // col group -> cols tx*4..+3
    const int ty = t >> 5;    // row group -> rows ty*4..+3
    const int c0t = tx * 4;

    float acc[4][4];
    #pragma unroll
    for (int i = 0; i < 4; ++i)
        #pragma unroll
        for (int j = 0; j < 4; ++j) acc[i][j] = 0.f;

    for (int kt = 0; kt < DIM; kt += 64) {
        #pragma unroll
        for (int i = 0; i < 2; ++i) {
            int fidx = (t + i * 256) * 4;
            int r = fidx >> 6;
            int k = fidx & 63;
            int gr = row0 + r;
            float4 v = make_float4(0.f, 0.f, 0.f, 0.f);
            if (gr < N) v = *(const float4*)(A + (size_t)gr * DIM + kt + k);
            *(float4*)(As + r * 68 + k) = v;
        }
        __syncthreads();

        #pragma unroll 4
        for (int k = 0; k < 64; k += 4) {
            float a[4][4];
            float w[4][4];
            #pragma unroll
            for (int i = 0; i < 4; ++i)
                *(float4*)a[i] = *(const float4*)(As + (ty * 4 + i) * 68 + k);
            #pragma unroll
            for (int kk = 0; kk < 4; ++kk)
                *(float4*)w[kk] = *(const float4*)(Ws + (kt + k + kk) * GTN + c0t);
            #pragma unroll
            for (int kk = 0; kk < 4; ++kk)
                #pragma unroll
                for (int i = 0; i < 4; ++i)
                    #pragma unroll
                    for (int j = 0; j < 4; ++j)
                        acc[i][j] += a[i][kk] * w[kk][j];
        }
        __syncthreads();
    }

    float bb[4];
    #pragma unroll
    for (int j = 0; j < 4; ++j) bb[j] = bias[c0t + j];
    #pragma unroll
    for (int i = 0; i < 4; ++i) {
        int gr = row0 + ty * 4 + i;
        if (gr < N) {
            float s = postscale ? postscale[gr] : 1.f;
            float4 o;
            o.x = fmaxf(acc[i][0] + bb[0], 0.f) * s;
            o.y = fmaxf(acc[i][1] + bb[1], 0.f) * s;
            o.z = fmaxf(acc[i][2] + bb[2], 0.f) * s;
            o.w = fmaxf(acc[i][3] + bb[3], 0.f) * s;
            *(float4*)(out + (size_t)gr * DIM + c0t) = o;
        }
    }
}

static inline size_t align_up(size_t x, size_t a) { return (x + a - 1) & ~(a - 1); }

extern "C" void kernel_launch(void* const* d_in, const int* in_sizes, int n_in,
                              void* d_out, int out_size, void* d_ws, size_t ws_size,
                              hipStream_t stream) {
    const float* features = (const float*)d_in[0];
    const int*   src      = (const int*)d_in[1];
    const int*   dst      = (const int*)d_in[2];
    const float* W1       = (const float*)d_in[3];
    const float* b1       = (const float*)d_in[4];
    const float* W2       = (const float*)d_in[5];
    const float* b2       = (const float*)d_in[6];
    float* out = (float*)d_out;

    const int N = in_sizes[0] / DIM;
    const int E = in_sizes[1];
    const int B = (N + 255) / 256;
    const int W2w = (N + 1) >> 1;                 // packed histogram words
    const int slice = (E + HB - 1) / HB;

    // workspace carve-up
    size_t nodeb = align_up((size_t)N * 4, 256);
    char* p = (char*)d_ws;
    int*   deg_out  = (int*)p;                      p += nodeb;
    int*   cnt      = (int*)p;                      p += nodeb;
    float* norm_src = (float*)p;                    p += nodeb;
    float* norm_dst = (float*)p;                    p += nodeb;
    int*   row_off  = (int*)p;                      p += align_up((size_t)(N + 1) * 4, 256);
    int*   bsum     = (int*)p;                      p += align_up((size_t)B * 4, 256);
    int*   bpre     = (int*)p;                      p += align_up((size_t)B * 4, 256);
    int*   csr_src  = (int*)p;                      p += align_up((size_t)E * 4, 256);
    float* agg      = (float*)p;                    p += (size_t)N * DIM * 4;
    float* h1       = (float*)p;                    p += (size_t)N * DIM * 4;
    // aliases over agg+h1 (51.2 MB, all dead before k_spmm writes agg):
    char* ap = (char*)agg;
    unsigned short* local = (unsigned short*)ap;    ap += align_up((size_t)E * 2, 256);
    unsigned* hist_in  = (unsigned*)ap;             ap += (size_t)HB * W2w * 4;
    unsigned* hist_out = (unsigned*)ap;             ap += (size_t)HB * W2w * 4;
    int* local_fb = (int*)agg;                      // fallback path only

    const int edge_blocks = (E + 255) / 256;
    const int spmm_blocks = (int)(((size_t)N * 32 + 255) / 256);
    const int gemm_blocks = (N + GTM - 1) / GTM;
    const int cs_blocks   = (W2w + 255) / 256;

    const bool fast = (W2w <= HWORDS) &&
        (align_up((size_t)E * 2, 256) + 2 * (size_t)HB * W2w * 4 <= 2 * (size_t)N * DIM * 4);

    if (fast) {
        // atomic-free graph build: LDS-private histograms on all CUs + column scan
        k_hist<<<HB, 256, 0, stream>>>(src, dst, local, hist_in, hist_out, E, W2w, slice);
        k_colscan<<<cs_blocks, 256, 0, stream>>>(hist_in, hist_out, cnt, deg_out, W2w, N, HB);
        k_block_reduce<<<B, 256, 0, stream>>>(cnt, bsum, N);
        k_scan_small<<<1, 256, 0, stream>>>(bsum, bpre, B);
        k_scan_final<<<B, 256, 0, stream>>>(cnt, deg_out, bpre, row_off, norm_src, norm_dst, N);
        k_fill<<<edge_blocks, 256, 0, stream>>>(src, dst, row_off, local, (const int*)nullptr,
                                                hist_in, csr_src, E, W2w, slice);
    } else {
        hipMemsetAsync(deg_out, 0, nodeb * 2, stream);  // deg_out, cnt
        k_edge_pass_fb<<<edge_blocks, 256, 0, stream>>>(src, dst, deg_out, cnt, local_fb, E);
        k_block_reduce<<<B, 256, 0, stream>>>(cnt, bsum, N);
        k_scan_small<<<1, 256, 0, stream>>>(bsum, bpre, B);
        k_scan_final<<<B, 256, 0, stream>>>(cnt, deg_out, bpre, row_off, norm_src, norm_dst, N);
        k_fill<<<edge_blocks, 256, 0, stream>>>(src, dst, row_off, (const unsigned short*)nullptr,
                                                local_fb, (const unsigned*)nullptr, csr_src, E, W2w, slice);
    }

    // layer 1: spmm gathers features with norm_src; gemm epilogue pre-scales h1 by norm_src
    k_spmm<<<spmm_blocks, 256, 0, stream>>>(features, csr_src, row_off, norm_src, norm_dst, agg, N);
    k_gemm_bias_relu<<<gemm_blocks, 256, 0, stream>>>(agg, W1, b1, norm_src, h1, N);

    // layer 2: h1 already carries norm_src; final gemm unscaled
    k_spmm<<<spmm_blocks, 256, 0, stream>>>(h1, csr_src, row_off, (const float*)nullptr, norm_dst, agg, N);
    k_gemm_bias_relu<<<gemm_blocks, 256, 0, stream>>>(agg, W2, b2, (const float*)nullptr, out, N);
}

// Round 8
// 296.100 us; speedup vs baseline: 1.1154x; 1.1154x over previous
//
#include <hip/hip_runtime.h>

#define DIM 128      // feature dim, fixed per reference
#define GTM 32       // gemm tile rows
#define GTN 128      // gemm tile cols (= DIM, A read once)
#define NCH 8        // colscan chunks
#define CH  30       // copies per chunk
#define HB  (NCH*CH) // 240 histogram copies ~= CU count (1 block/CU, 100KB LDS)
#define HWORDS 25088 // max (N+1)/2 supported by LDS histogram (100,352 B)

// ---------------- LDS-privatized dual histogram + rank capture ----------------
__global__ __launch_bounds__(256) void k_hist(const int* __restrict__ src,
                                              const int* __restrict__ dst,
                                              unsigned short* __restrict__ local,
                                              unsigned* __restrict__ hist_in,
                                              unsigned* __restrict__ hist_out,
                                              int E, int W2, int slice) {
    __shared__ unsigned h[HWORDS];
    const int t = threadIdx.x;
    const int b = blockIdx.x;
    const int e0 = b * slice;
    const int e1 = min(e0 + slice, E);

    for (int w = t; w < W2; w += 256) h[w] = 0u;
    __syncthreads();
    for (int e = e0 + t; e < e1; e += 256) {
        int d = dst[e];
        unsigned sh = (unsigned)(d & 1) * 16u;
        unsigned old = atomicAdd(&h[d >> 1], 1u << sh);
        local[e] = (unsigned short)((old >> sh) & 0xffffu);
    }
    __syncthreads();
    unsigned* oin = hist_in + (size_t)b * W2;
    for (int w = t; w < W2; w += 256) { oin[w] = h[w]; h[w] = 0u; }
    __syncthreads();
    for (int e = e0 + t; e < e1; e += 256) {
        int s = src[e];
        atomicAdd(&h[s >> 1], 1u << ((unsigned)(s & 1) * 16u));
    }
    __syncthreads();
    unsigned* oout = hist_out + (size_t)b * W2;
    for (int w = t; w < W2; w += 256) oout[w] = h[w];
}

// ---------------- colscan pass 1: in-chunk exclusive prefix + chunk totals ----------------
// grid (W2/256, NCH): 8x the parallelism of a flat scan; chain length 30 not 240.
__global__ __launch_bounds__(256) void k_colscan1(unsigned* __restrict__ hist_in,
                                                  const unsigned* __restrict__ hist_out,
                                                  unsigned* __restrict__ aux_in,
                                                  unsigned* __restrict__ aux_out, int W2) {
    int w = blockIdx.x * 256 + threadIdx.x;
    if (w >= W2) return;
    int ch = blockIdx.y;
    size_t base = (size_t)ch * CH * W2 + w;
    unsigned run = 0;
    #pragma unroll 5
    for (int b = 0; b < CH; ++b) {
        unsigned* p = hist_in + base + (size_t)b * W2;
        unsigned x = *p;
        *p = run;          // in-chunk exclusive packed prefix
        run += x;          // halves independent (each < 65536)
    }
    aux_in[(size_t)ch * W2 + w] = run;
    unsigned run2 = 0;
    #pragma unroll 5
    for (int b = 0; b < CH; ++b) run2 += hist_out[base + (size_t)b * W2];
    aux_out[(size_t)ch * W2 + w] = run2;
}

// ---------------- colscan pass 2: scan chunk totals -> bases; totals -> cnt/deg_out ----------------
__global__ __launch_bounds__(256) void k_colscan2(unsigned* __restrict__ aux_in,
                                                  const unsigned* __restrict__ aux_out,
                                                  int* __restrict__ cnt,
                                                  int* __restrict__ deg_out,
                                                  int W2, int N) {
    int w = blockIdx.x * 256 + threadIdx.x;
    if (w >= W2) return;
    unsigned run = 0, run2 = 0;
    #pragma unroll
    for (int ch = 0; ch < NCH; ++ch) {
        unsigned x = aux_in[(size_t)ch * W2 + w];
        aux_in[(size_t)ch * W2 + w] = run;   // chunk base
        run += x;
        run2 += aux_out[(size_t)ch * W2 + w];
    }
    int n0 = w * 2, n1 = n0 + 1;
    cnt[n0] = (int)(run & 0xffffu);
    deg_out[n0] = (int)(run2 & 0xffffu);
    if (n1 < N) {
        cnt[n1] = (int)(run >> 16);
        deg_out[n1] = (int)(run2 >> 16);
    }
}

// ---------------- fallback edge pass (global atomics) for oversized N ----------------
__global__ __launch_bounds__(256) void k_edge_pass_fb(const int* __restrict__ src,
                                                      const int* __restrict__ dst,
                                                      int* __restrict__ deg_out,
                                                      int* __restrict__ cnt,
                                                      int* __restrict__ local_fb, int E) {
    int e = blockIdx.x * 256 + threadIdx.x;
    if (e < E) {
        atomicAdd(&deg_out[src[e]], 1);
        local_fb[e] = atomicAdd(&cnt[dst[e]], 1);
    }
}

// ---------------- fallback norms ----------------
__global__ __launch_bounds__(256) void k_norms_fb(const int* __restrict__ deg_out,
                                                  const int* __restrict__ cnt,
                                                  float* __restrict__ norm_src,
                                                  float* __restrict__ norm_dst, int N) {
    int i = blockIdx.x * 256 + threadIdx.x;
    if (i < N) {
        int dov = deg_out[i]; if (dov < 1) dov = 1;
        int div_ = cnt[i]; if (div_ < 1) div_ = 1;
        norm_src[i] = rsqrtf((float)dov);
        norm_dst[i] = rsqrtf((float)div_);
    }
}

// ---------------- scan step 1: per-block sums of cnt ----------------
__global__ __launch_bounds__(256) void k_block_reduce(const int* __restrict__ deg,
                                                      int* __restrict__ bsum, int N) {
    __shared__ int wsum[4];
    int i = blockIdx.x * 256 + threadIdx.x;
    int x = (i < N) ? deg[i] : 0;
    #pragma unroll
    for (int off = 32; off > 0; off >>= 1) x += __shfl_down(x, off, 64);
    int lane = threadIdx.x & 63, wave = threadIdx.x >> 6;
    if (lane == 0) wsum[wave] = x;
    __syncthreads();
    if (threadIdx.x == 0) bsum[blockIdx.x] = wsum[0] + wsum[1] + wsum[2] + wsum[3];
}

// ---------------- scan step 2: exclusive scan of block sums (1 block) ----------------
__global__ __launch_bounds__(256) void k_scan_small(const int* __restrict__ bsum,
                                                    int* __restrict__ bpre, int B) {
    __shared__ int wsum[4];
    __shared__ int carry_s;
    if (threadIdx.x == 0) carry_s = 0;
    __syncthreads();
    int lane = threadIdx.x & 63, wave = threadIdx.x >> 6;
    for (int base = 0; base < B; base += 256) {
        int i = base + threadIdx.x;
        int x = (i < B) ? bsum[i] : 0;
        int orig = x;
        #pragma unroll
        for (int off = 1; off < 64; off <<= 1) {
            int y = __shfl_up(x, off, 64);
            if (lane >= off) x += y;
        }
        if (lane == 63) wsum[wave] = x;
        __syncthreads();
        if (threadIdx.x == 0) {
            int s = 0;
            for (int w = 0; w < 4; ++w) { int t = wsum[w]; wsum[w] = s; s += t; }
        }
        __syncthreads();
        x += wsum[wave] + carry_s;
        if (i < B) bpre[i] = x - orig;
        __syncthreads();
        if (threadIdx.x == 255) carry_s = x;
        __syncthreads();
    }
}

// ---------------- scan step 3: row_off + both norms (fused) ----------------
__global__ __launch_bounds__(256) void k_scan_final(const int* __restrict__ cnt,
                                                    const int* __restrict__ deg_out,
                                                    const int* __restrict__ bpre,
                                                    int* __restrict__ row_off,
                                                    float* __restrict__ norm_src,
                                                    float* __restrict__ norm_dst, int N) {
    __shared__ int wsum[4];
    int i = blockIdx.x * 256 + threadIdx.x;
    int x = (i < N) ? cnt[i] : 0;
    int orig = x;
    int lane = threadIdx.x & 63, wave = threadIdx.x >> 6;
    #pragma unroll
    for (int off = 1; off < 64; off <<= 1) {
        int y = __shfl_up(x, off, 64);
        if (lane >= off) x += y;
    }
    if (lane == 63) wsum[wave] = x;
    __syncthreads();
    if (threadIdx.x == 0) {
        int s = 0;
        for (int w = 0; w < 4; ++w) { int t = wsum[w]; wsum[w] = s; s += t; }
    }
    __syncthreads();
    x += wsum[wave] + bpre[blockIdx.x];
    if (i < N) {
        row_off[i] = x - orig;
        int di = orig < 1 ? 1 : orig;
        norm_dst[i] = rsqrtf((float)di);
        int dov = deg_out[i]; if (dov < 1) dov = 1;
        norm_src[i] = rsqrtf((float)dov);
    }
    if (i == N - 1) row_off[N] = x;
}

// ---------------- CSR fill: pure scatter, no atomics ----------------
// fast: pos = row_off + chunk base (aux_in) + in-chunk block offset (hist_in) + rank
__global__ __launch_bounds__(256) void k_fill(const int* __restrict__ src,
                                              const int* __restrict__ dst,
                                              const int* __restrict__ row_off,
                                              const unsigned short* __restrict__ local,
                                              const int* __restrict__ local_fb,
                                              const unsigned* __restrict__ hist_in,
                                              const unsigned* __restrict__ aux_in,
                                              int* __restrict__ csr_src,
                                              int E, int W2, int slice) {
    int e = blockIdx.x * 256 + threadIdx.x;
    if (e < E) {
        int d = dst[e];
        int pos = row_off[d];
        if (hist_in) {
            int b = e / slice;
            int ch = b / CH;
            unsigned sh = (unsigned)(d & 1) * 16u;
            unsigned bo = (hist_in[(size_t)b * W2 + (d >> 1)] >> sh) & 0xffffu;
            unsigned cb = (aux_in[(size_t)ch * W2 + (d >> 1)] >> sh) & 0xffffu;
            pos += (int)bo + (int)cb + (int)local[e];
        } else {
            pos += local_fb[e];
        }
        csr_src[pos] = src[e];
    }
}

// ---------------- CSR SpMM: agg[d] = nd[d] * sum_s w(s)*h[s] ----------------
__global__ __launch_bounds__(256) void k_spmm(const float* __restrict__ h,
                                              const int* __restrict__ csr_src,
                                              const int* __restrict__ row_off,
                                              const float* __restrict__ norm_src,
                                              const float* __restrict__ norm_dst,
                                              float* __restrict__ agg, int N) {
    int t = blockIdx.x * 256 + threadIdx.x;
    int node = t >> 5;
    int lane = t & 31;
    if (node >= N) return;
    int beg = row_off[node], end = row_off[node + 1];
    float4 acc0 = make_float4(0.f, 0.f, 0.f, 0.f);
    float4 acc1 = make_float4(0.f, 0.f, 0.f, 0.f);
    int i = beg;
    if (norm_src) {
        for (; i + 4 <= end; i += 4) {
            int s0 = csr_src[i], s1 = csr_src[i + 1], s2 = csr_src[i + 2], s3 = csr_src[i + 3];
            float n0 = norm_src[s0], n1 = norm_src[s1], n2 = norm_src[s2], n3 = norm_src[s3];
            float4 v0 = *((const float4*)(h + (size_t)s0 * DIM) + lane);
            float4 v1 = *((const float4*)(h + (size_t)s1 * DIM) + lane);
            float4 v2 = *((const float4*)(h + (size_t)s2 * DIM) + lane);
            float4 v3 = *((const float4*)(h + (size_t)s3 * DIM) + lane);
            acc0.x += v0.x * n0; acc0.y += v0.y * n0; acc0.z += v0.z * n0; acc0.w += v0.w * n0;
            acc1.x += v1.x * n1; acc1.y += v1.y * n1; acc1.z += v1.z * n1; acc1.w += v1.w * n1;
            acc0.x += v2.x * n2; acc0.y += v2.y * n2; acc0.z += v2.z * n2; acc0.w += v2.w * n2;
            acc1.x += v3.x * n3; acc1.y += v3.y * n3; acc1.z += v3.z * n3; acc1.w += v3.w * n3;
        }
        for (; i < end; ++i) {
            int s0 = csr_src[i];
            float n0 = norm_src[s0];
            float4 v0 = *((const float4*)(h + (size_t)s0 * DIM) + lane);
            acc0.x += v0.x * n0; acc0.y += v0.y * n0; acc0.z += v0.z * n0; acc0.w += v0.w * n0;
        }
    } else {
        for (; i + 4 <= end; i += 4) {
            int s0 = csr_src[i], s1 = csr_src[i + 1], s2 = csr_src[i + 2], s3 = csr_src[i + 3];
            float4 v0 = *((const float4*)(h + (size_t)s0 * DIM) + lane);
            float4 v1 = *((const float4*)(h + (size_t)s1 * DIM) + lane);
            float4 v2 = *((const float4*)(h + (size_t)s2 * DIM) + lane);
            float4 v3 = *((const float4*)(h + (size_t)s3 * DIM) + lane);
            acc0.x += v0.x; acc0.y += v0.y; acc0.z += v0.z; acc0.w += v0.w;
            acc1.x += v1.x; acc1.y += v1.y; acc1.z += v1.z; acc1.w += v1.w;
            acc0.x += v2.x; acc0.y += v2.y; acc0.z += v2.z; acc0.w += v2.w;
            acc1.x += v3.x; acc1.y += v3.y; acc1.z += v3.z; acc1.w += v3.w;
        }
        for (; i < end; ++i) {
            int s0 = csr_src[i];
            float4 v0 = *((const float4*)(h + (size_t)s0 * DIM) + lane);
            acc0.x += v0.x; acc0.y += v0.y; acc0.z += v0.z; acc0.w += v0.w;
        }
    }
    float nd = norm_dst[node];
    float4 o;
    o.x = (acc0.x + acc1.x) * nd;
    o.y = (acc0.y + acc1.y) * nd;
    o.z = (acc0.z + acc1.z) * nd;
    o.w = (acc0.w + acc1.w) * nd;
    *((float4*)(agg + (size_t)node * DIM) + lane) = o;
}

// ---------------- fused: out = [postscale ⊙] relu(agg @ W + b) ----------------
__global__ __launch_bounds__(256, 2) void k_gemm_bias_relu(
        const float* __restrict__ A, const float* __restrict__ W,
        const float* __restrict__ bias, const float* __restrict__ postscale,
        float* __restrict__ out, int N) {
    __shared__ float Ws[DIM * GTN];   // [k][c] 64 KB
    __shared__ float As[GTM * 68];    // [r][64-k chunk], stride 68

    const int t = threadIdx.x;
    const int row0 = blockIdx.x * GTM;

    #pragma unroll
    for (int i = 0; i < 16; ++i) {
        int idx = (t + i * 256) * 4;
        *(float4*)(Ws + idx) = *(const float4*)(W + idx);
    }

    const int tx = t & 31;
    const int ty = t >> 5;
    const int c0t = tx * 4;

    float acc[4][4];
    #pragma unroll
    for (int i = 0; i < 4; ++i)
        #pragma unroll
        for (int j = 0; j < 4; ++j) acc[i][j] = 0.f;

    for (int kt = 0; kt < DIM; kt += 64) {
        #pragma unroll
        for (int i = 0; i < 2; ++i) {
            int fidx = (t + i * 256) * 4;
            int r = fidx >> 6;
            int k = fidx & 63;
            int gr = row0 + r;
            float4 v = make_float4(0.f, 0.f, 0.f, 0.f);
            if (gr < N) v = *(const float4*)(A + (size_t)gr * DIM + kt + k);
            *(float4*)(As + r * 68 + k) = v;
        }
        __syncthreads();

        #pragma unroll 4
        for (int k = 0; k < 64; k += 4) {
            float a[4][4];
            float w[4][4];
            #pragma unroll
            for (int i = 0; i < 4; ++i)
                *(float4*)a[i] = *(const float4*)(As + (ty * 4 + i) * 68 + k);
            #pragma unroll
            for (int kk = 0; kk < 4; ++kk)
                *(float4*)w[kk] = *(const float4*)(Ws + (kt + k + kk) * GTN + c0t);
            #pragma unroll
            for (int kk = 0; kk < 4; ++kk)
                #pragma unroll
                for (int i = 0; i < 4; ++i)
                    #pragma unroll
                    for (int j = 0; j < 4; ++j)
                        acc[i][j] += a[i][kk] * w[kk][j];
        }
        __syncthreads();
    }

    float bb[4];
    #pragma unroll
    for (int j = 0; j < 4; ++j) bb[j] = bias[c0t + j];
    #pragma unroll
    for (int i = 0; i < 4; ++i) {
        int gr = row0 + ty * 4 + i;
        if (gr < N) {
            float s = postscale ? postscale[gr] : 1.f;
            float4 o;
            o.x = fmaxf(acc[i][0] + bb[0], 0.f) * s;
            o.y = fmaxf(acc[i][1] + bb[1], 0.f) * s;
            o.z = fmaxf(acc[i][2] + bb[2], 0.f) * s;
            o.w = fmaxf(acc[i][3] + bb[3], 0.f) * s;
            *(float4*)(out + (size_t)gr * DIM + c0t) = o;
        }
    }
}

static inline size_t align_up(size_t x, size_t a) { return (x + a - 1) & ~(a - 1); }

extern "C" void kernel_launch(void* const* d_in, const int* in_sizes, int n_in,
                              void* d_out, int out_size, void* d_ws, size_t ws_size,
                              hipStream_t stream) {
    const float* features = (const float*)d_in[0];
    const int*   src      = (const int*)d_in[1];
    const int*   dst      = (const int*)d_in[2];
    const float* W1       = (const float*)d_in[3];
    const float* b1       = (const float*)d_in[4];
    const float* W2       = (const float*)d_in[5];
    const float* b2       = (const float*)d_in[6];
    float* out = (float*)d_out;

    const int N = in_sizes[0] / DIM;
    const int E = in_sizes[1];
    const int B = (N + 255) / 256;
    const int W2w = (N + 1) >> 1;                 // packed histogram words
    const int slice = (E + HB - 1) / HB;

    // workspace carve-up
    size_t nodeb = align_up((size_t)N * 4, 256);
    char* p = (char*)d_ws;
    int*   deg_out  = (int*)p;                      p += nodeb;
    int*   cnt      = (int*)p;                      p += nodeb;
    float* norm_src = (float*)p;                    p += nodeb;
    float* norm_dst = (float*)p;                    p += nodeb;
    int*   row_off  = (int*)p;                      p += align_up((size_t)(N + 1) * 4, 256);
    int*   bsum     = (int*)p;                      p += align_up((size_t)B * 4, 256);
    int*   bpre     = (int*)p;                      p += align_up((size_t)B * 4, 256);
    int*   csr_src  = (int*)p;                      p += align_up((size_t)E * 4, 256);
    float* agg      = (float*)p;                    p += (size_t)N * DIM * 4;
    float* h1       = (float*)p;                    p += (size_t)N * DIM * 4;
    // aliases over agg+h1 (51.2 MB, all dead before k_spmm writes agg):
    char* ap = (char*)agg;
    unsigned short* local = (unsigned short*)ap;    ap += align_up((size_t)E * 2, 256);
    unsigned* hist_in  = (unsigned*)ap;             ap += (size_t)HB * W2w * 4;
    unsigned* hist_out = (unsigned*)ap;             ap += (size_t)HB * W2w * 4;
    unsigned* aux_in   = (unsigned*)ap;             ap += (size_t)NCH * W2w * 4;
    unsigned* aux_out  = (unsigned*)ap;             ap += (size_t)NCH * W2w * 4;
    int* local_fb = (int*)agg;                      // fallback path only

    const int edge_blocks = (E + 255) / 256;
    const int spmm_blocks = (int)(((size_t)N * 32 + 255) / 256);
    const int gemm_blocks = (N + GTM - 1) / GTM;
    const int cs_blocks   = (W2w + 255) / 256;

    const bool fast = (W2w <= HWORDS) &&
        (align_up((size_t)E * 2, 256) + (2 * (size_t)HB + 2 * NCH) * W2w * 4
            <= 2 * (size_t)N * DIM * 4);

    if (fast) {
        k_hist<<<HB, 256, 0, stream>>>(src, dst, local, hist_in, hist_out, E, W2w, slice);
        k_colscan1<<<dim3(cs_blocks, NCH), 256, 0, stream>>>(hist_in, hist_out, aux_in, aux_out, W2w);
        k_colscan2<<<cs_blocks, 256, 0, stream>>>(aux_in, aux_out, cnt, deg_out, W2w, N);
        k_block_reduce<<<B, 256, 0, stream>>>(cnt, bsum, N);
        k_scan_small<<<1, 256, 0, stream>>>(bsum, bpre, B);
        k_scan_final<<<B, 256, 0, stream>>>(cnt, deg_out, bpre, row_off, norm_src, norm_dst, N);
        k_fill<<<edge_blocks, 256, 0, stream>>>(src, dst, row_off, local, (const int*)nullptr,
                                                hist_in, aux_in, csr_src, E, W2w, slice);
    } else {
        hipMemsetAsync(deg_out, 0, nodeb * 2, stream);
        k_edge_pass_fb<<<edge_blocks, 256, 0, stream>>>(src, dst, deg_out, cnt, local_fb, E);
        k_block_reduce<<<B, 256, 0, stream>>>(cnt, bsum, N);
        k_scan_small<<<1, 256, 0, stream>>>(bsum, bpre, B);
        k_scan_final<<<B, 256, 0, stream>>>(cnt, deg_out, bpre, row_off, norm_src, norm_dst, N);
        k_fill<<<edge_blocks, 256, 0, stream>>>(src, dst, row_off, (const unsigned short*)nullptr,
                                                local_fb, (const unsigned*)nullptr, (const unsigned*)nullptr,
                                                csr_src, E, W2w, slice);
    }

    // layer 1: spmm gathers features with norm_src; gemm epilogue pre-scales h1 by norm_src
    k_spmm<<<spmm_blocks, 256, 0, stream>>>(features, csr_src, row_off, norm_src, norm_dst, agg, N);
    k_gemm_bias_relu<<<gemm_blocks, 256, 0, stream>>>(agg, W1, b1, norm_src, h1, N);

    // layer 2: h1 already carries norm_src; final gemm unscaled
    k_spmm<<<spmm_blocks, 256, 0, stream>>>(h1, csr_src, row_off, (const float*)nullptr, norm_dst, agg, N);
    k_gemm_bias_relu<<<gemm_blocks, 256, 0, stream>>>(agg, W2, b2, (const float*)nullptr, out, N);
}